// Round 10
// baseline (234.880 us; speedup 1.0000x reference)
//
#include <hip/hip_runtime.h>

// ExpanderLinearLayer: out[M,N] = input[M,K] @ (W[N,K]*mask[N,K])^T
// M=16384, N=2048, K=2048, fp32 in/out.
// bf16 conversion + 256x256 MFMA GEMM (16x16x32), 8 waves x (128x64), 8x4 acc.
// KEY CHANGE (R9 post-mortem): LDS pipe was saturated (96-120KB/block-phase
// @ ~85 B/cyc > MFMA 1242 cyc -> MfmaUtil pinned ~37%). B operands now load
// DIRECTLY from global (L2/L3-resident, 8 MB) into registers; LDS holds A
// only (4-slot ring, 64 KiB) -> 80 KB/block-phase < MFMA window.
// Per phase: {STGA(t+3); LDB(t+1); VMCNT(6); bar; 8 A ds_reads; 32 MFMA; bar}.

#define MDIM 16384
#define NDIM 2048
#define KDIM 2048

#define BM 256
#define BN 256
#define GRID_X ((MDIM / BM) * (NDIM / BN))  // 64*8 = 512

using f32x4   = __attribute__((ext_vector_type(4))) float;
using bf16x8  = __attribute__((ext_vector_type(8))) __bf16;
using ushort8 = __attribute__((ext_vector_type(8))) unsigned short;

__device__ __forceinline__ unsigned short f2bf(float f) {
  unsigned int u = __builtin_bit_cast(unsigned int, f);
  u = u + 0x7FFFu + ((u >> 16) & 1u);  // RNE
  return (unsigned short)(u >> 16);
}

// ---------------- conversion kernels ----------------

__global__ void convert_input_kernel(const float* __restrict__ in,
                                     unsigned short* __restrict__ out) {
  size_t base = ((size_t)blockIdx.x * blockDim.x + threadIdx.x) * 8;
  float4 a = *reinterpret_cast<const float4*>(in + base);
  float4 b = *reinterpret_cast<const float4*>(in + base + 4);
  ushort8 v;
  v[0] = f2bf(a.x); v[1] = f2bf(a.y); v[2] = f2bf(a.z); v[3] = f2bf(a.w);
  v[4] = f2bf(b.x); v[5] = f2bf(b.y); v[6] = f2bf(b.z); v[7] = f2bf(b.w);
  *reinterpret_cast<ushort8*>(out + base) = v;
}

__global__ void convert_weight_kernel(const float* __restrict__ w,
                                      const int* __restrict__ mk,
                                      unsigned short* __restrict__ out) {
  size_t base = ((size_t)blockIdx.x * blockDim.x + threadIdx.x) * 8;
  float4 a = *reinterpret_cast<const float4*>(w + base);
  float4 b = *reinterpret_cast<const float4*>(w + base + 4);
  int4 m0 = *reinterpret_cast<const int4*>(mk + base);
  int4 m1 = *reinterpret_cast<const int4*>(mk + base + 4);
  ushort8 v;
  v[0] = m0.x ? f2bf(a.x) : (unsigned short)0;
  v[1] = m0.y ? f2bf(a.y) : (unsigned short)0;
  v[2] = m0.z ? f2bf(a.z) : (unsigned short)0;
  v[3] = m0.w ? f2bf(a.w) : (unsigned short)0;
  v[4] = m1.x ? f2bf(b.x) : (unsigned short)0;
  v[5] = m1.y ? f2bf(b.y) : (unsigned short)0;
  v[6] = m1.z ? f2bf(b.z) : (unsigned short)0;
  v[7] = m1.w ? f2bf(b.w) : (unsigned short)0;
  *reinterpret_cast<ushort8*>(out + base) = v;
}

// ---------------- B-in-registers GEMM ----------------

__device__ __forceinline__ f32x4 MF(bf16x8 a, bf16x8 b, f32x4 c) {
  return __builtin_amdgcn_mfma_f32_16x16x32_bf16(a, b, c, 0, 0, 0);
}
__device__ __forceinline__ void bar() {
  asm volatile("" ::: "memory");
  __builtin_amdgcn_s_barrier();
  asm volatile("" ::: "memory");
}
#define VMCNT(n) asm volatile("s_waitcnt vmcnt(" #n ")" ::: "memory")

// LDS: A only, ring of 4 slots [256 rows][32 k] bf16 (16 KiB each, 64 KiB).
// Phase t consumes slot t%4; slot t+3 staged at t (flight >= 1 phase > HBM
// lat after steady state). Swizzle (verified conflict-free R3): 16-B chunk'
// = chunk ^ ((row>>1)&3) on pre-swizzled global source + ds_read addrs.
// B: per-lane global_load_dwordx4 of the exact MFMA frag, double-buffered
// regs, prefetch distance 1 phase; 4 persistent base pointers, compile-time
// k offsets (<= 4032 B, fits 13-bit signed imm).
__global__ __launch_bounds__(512, 2) void gemm_breg(
    const unsigned short* __restrict__ Abf,
    const unsigned short* __restrict__ Bbf,
    float* __restrict__ C) {
  __shared__ __attribute__((aligned(16))) unsigned short Asl[4 * 8192];

  // bijective XCD swizzle (512 % 8 == 0) -- R3's proven map (FETCH ~98 MB)
  int bid = blockIdx.x;
  int wgs = (bid & 7) * (GRID_X / 8) + (bid >> 3);
  int tm = wgs >> 3;  // NDIM/BN == 8
  int tn = wgs & 7;
  int row0 = tm * BM, col0 = tn * BN;

  int t = threadIdx.x;
  int lane = t & 63, wid = t >> 6;
  int wr = wid >> 2, wc = wid & 3;       // 2 x 4 wave grid, wave tile 128x64
  int fr = lane & 15, fq = lane >> 4;

  // A staging: thread covers chunks p0 and p0+64 (rows r0, r0+16; swizzle key
  // (r>>1)&3 invariant under +16 rows -> same inverse-swizzled k-chunk).
  int p0 = (wid * 2) * 64 + lane;
  int r0 = p0 >> 2, kc0 = ((p0 & 3) ^ ((r0 >> 1) & 3)) * 8;
  size_t offA0 = (size_t)(row0 + r0) * KDIM + kc0;
  int ldsw0 = (wid * 2) * 512;  // elements; wave-uniform

  // A frag ds_read offsets
  int kxor = (fq ^ ((fr >> 1) & 3)) * 8;
  int aoff = (wr * 128 + fr) * 32 + kxor;

  // B frag global base pointers (n = 0..3): row col0 + wc*64 + n*16 + fr,
  // k base fq*8. Per-phase k offset added as compile-time immediate.
  size_t offB = (size_t)(col0 + wc * 64 + fr) * KDIM + fq * 8;
  const unsigned short* bp0 = Bbf + offB;
  const unsigned short* bp1 = bp0 + 16 * KDIM;
  const unsigned short* bp2 = bp0 + 32 * KDIM;
  const unsigned short* bp3 = bp0 + 48 * KDIM;

  f32x4 acc[8][4];
#pragma unroll
  for (int m = 0; m < 8; ++m)
#pragma unroll
    for (int n = 0; n < 4; ++n) acc[m][n] = f32x4{0.f, 0.f, 0.f, 0.f};

  bf16x8 afr[8], bP[4], bQ[4];

#define STGA(sa, ke) do {                                                       \
  __builtin_amdgcn_global_load_lds(                                             \
      (const __attribute__((address_space(1))) void*)(Abf + offA0 + (ke)),      \
      (__attribute__((address_space(3))) void*)(Asl + (sa) * 8192 + ldsw0),     \
      16, 0, 0);                                                                \
  __builtin_amdgcn_global_load_lds(                                             \
      (const __attribute__((address_space(1))) void*)(Abf + offA0 + 32768 +     \
                                                      (ke)),                    \
      (__attribute__((address_space(3))) void*)(Asl + (sa) * 8192 + ldsw0 +     \
                                                512),                           \
      16, 0, 0);                                                                \
} while (0)

#define LDB(BUF, ke) do {                                                       \
  BUF[0] = *(const bf16x8*)(bp0 + (ke));                                        \
  BUF[1] = *(const bf16x8*)(bp1 + (ke));                                        \
  BUF[2] = *(const bf16x8*)(bp2 + (ke));                                        \
  BUF[3] = *(const bf16x8*)(bp3 + (ke));                                        \
} while (0)

// phase t: consume A slot sa (retired+published at t-1), B regs BC (loaded
// at t-1, retired by this phase's VMCNT); stage A(t+3), load B(t+1) into BL.
#define PH(sa, BC, BL, STAGES, WAITS) do {                                      \
  STAGES;                                                                       \
  WAITS;                                                                        \
  bar();                                                                        \
  const unsigned short* _ap = Asl + (sa) * 8192 + aoff;                         \
  _Pragma("unroll")                                                             \
  for (int _m = 0; _m < 8; ++_m) afr[_m] = *(const bf16x8*)(_ap + _m * 512);    \
  __builtin_amdgcn_s_setprio(1);                                                \
  _Pragma("unroll")                                                             \
  for (int _m = 0; _m < 8; ++_m)                                                \
    _Pragma("unroll")                                                           \
    for (int _n = 0; _n < 4; ++_n)                                              \
      acc[_m][_n] = MF(afr[_m], BC[_n], acc[_m][_n]);                           \
  __builtin_amdgcn_s_setprio(0);                                                \
  bar();                                                                        \
} while (0)

  // prologue: A slots 0,1,2 (6 gload_lds) + B(0) (4 loads). Phase 0's
  // VMCNT(6) retires A0,A1,A2,B(0), leaving A(3):2 + B(1):4 in flight.
  STGA(0, 0);
  STGA(1, 32);
  STGA(2, 64);
  LDB(bP, 0);

  // main loop: phases t = 0..59. Steady queue at wait: [A(t+2):2, B(t):4,
  // A(t+3):2, B(t+1):4] -> VMCNT(6) retires B(t) (+older A's), leaving 6.
  for (int i = 0; i < 15; ++i) {
    int kb = i * 128;
    PH(0, bP, bQ, { STGA(3, kb + 96);  LDB(bQ, kb + 32);  }, VMCNT(6));
    PH(1, bQ, bP, { STGA(0, kb + 128); LDB(bP, kb + 64);  }, VMCNT(6));
    PH(2, bP, bQ, { STGA(1, kb + 160); LDB(bQ, kb + 96);  }, VMCNT(6));
    PH(3, bQ, bP, { STGA(2, kb + 192); LDB(bP, kb + 128); }, VMCNT(6));
  }
  // tail: t = 60..63. A(63) staged at t=60; B continues to B(63).
  PH(0, bP, bQ, { STGA(3, 2016); LDB(bQ, 1952); }, VMCNT(6));  // t=60
  PH(1, bQ, bP, { LDB(bP, 1984); }, VMCNT(4));                 // t=61: B(62)
  PH(2, bP, bQ, { LDB(bQ, 2016); }, VMCNT(4));                 // t=62: B(63)
  PH(3, bQ, bP, , VMCNT(0));                                   // t=63

  // epilogue: C/D layout (verified m89) col=lane&15, row=(lane>>4)*4+reg
  size_t crow = (size_t)(row0 + wr * 128 + fq * 4);
  int ccol = col0 + wc * 64 + fr;
#pragma unroll
  for (int m = 0; m < 8; ++m)
#pragma unroll
    for (int n = 0; n < 4; ++n) {
      float* cp = C + (crow + m * 16) * NDIM + ccol + n * 16;
#pragma unroll
      for (int e = 0; e < 4; ++e) cp[(size_t)e * NDIM] = acc[m][n][e];
    }
#undef PH
#undef LDB
#undef STGA
}

// ---------------- fallback (fused conversion, 128^2 m97-structure) ----------

__global__ __launch_bounds__(256) void gemm_fused_fallback(
    const float* __restrict__ Afp,
    const float* __restrict__ Wfp,
    const int* __restrict__ Mk,
    float* __restrict__ C) {
  __shared__ unsigned short As[128 * 32];
  __shared__ unsigned short Bs[128 * 32];
  int bid = blockIdx.x;
  int nwg = (MDIM / 128) * (NDIM / 128);
  int wg = (bid & 7) * (nwg / 8) + (bid >> 3);
  int tm = wg >> 4, tn = wg & 15;
  int row0 = tm * 128, col0 = tn * 128;
  int t = threadIdx.x;
  int lane = t & 63, wv = t >> 6;
  int wr = wv >> 1, wc = wv & 1;
  int fr = lane & 15, fq = lane >> 4;
  f32x4 acc[4][4];
#pragma unroll
  for (int i = 0; i < 4; ++i)
#pragma unroll
    for (int j = 0; j < 4; ++j) acc[i][j] = f32x4{0.f, 0.f, 0.f, 0.f};
  for (int kt = 0; kt < KDIM; kt += 32) {
#pragma unroll
    for (int j = 0; j < 2; ++j) {
      int c = j * 256 + t;
      int r = c >> 2;
      int ko = (c & 3) * 8;
      const float* ga = Afp + (size_t)(row0 + r) * KDIM + kt + ko;
      float4 a0 = *reinterpret_cast<const float4*>(ga);
      float4 a1 = *reinterpret_cast<const float4*>(ga + 4);
      ushort8 va;
      va[0] = f2bf(a0.x); va[1] = f2bf(a0.y); va[2] = f2bf(a0.z); va[3] = f2bf(a0.w);
      va[4] = f2bf(a1.x); va[5] = f2bf(a1.y); va[6] = f2bf(a1.z); va[7] = f2bf(a1.w);
      *reinterpret_cast<ushort8*>(As + (size_t)c * 8) = va;
      const float* gw = Wfp + (size_t)(col0 + r) * KDIM + kt + ko;
      const int* gm = Mk + (size_t)(col0 + r) * KDIM + kt + ko;
      float4 w0 = *reinterpret_cast<const float4*>(gw);
      float4 w1 = *reinterpret_cast<const float4*>(gw + 4);
      int4 m0 = *reinterpret_cast<const int4*>(gm);
      int4 m1 = *reinterpret_cast<const int4*>(gm + 4);
      ushort8 vb;
      vb[0] = m0.x ? f2bf(w0.x) : (unsigned short)0;
      vb[1] = m0.y ? f2bf(w0.y) : (unsigned short)0;
      vb[2] = m0.z ? f2bf(w0.z) : (unsigned short)0;
      vb[3] = m0.w ? f2bf(w0.w) : (unsigned short)0;
      vb[4] = m1.x ? f2bf(w1.x) : (unsigned short)0;
      vb[5] = m1.y ? f2bf(w1.y) : (unsigned short)0;
      vb[6] = m1.z ? f2bf(w1.z) : (unsigned short)0;
      vb[7] = m1.w ? f2bf(w1.w) : (unsigned short)0;
      *reinterpret_cast<ushort8*>(Bs + (size_t)c * 8) = vb;
    }
    __syncthreads();
    bf16x8 af[4], bfr[4];
#pragma unroll
    for (int m2 = 0; m2 < 4; ++m2)
      af[m2] = *reinterpret_cast<const bf16x8*>(As + (wr * 64 + m2 * 16 + fr) * 32 + fq * 8);
#pragma unroll
    for (int n2 = 0; n2 < 4; ++n2)
      bfr[n2] = *reinterpret_cast<const bf16x8*>(Bs + (wc * 64 + n2 * 16 + fr) * 32 + fq * 8);
#pragma unroll
    for (int m2 = 0; m2 < 4; ++m2)
#pragma unroll
      for (int n2 = 0; n2 < 4; ++n2)
        acc[m2][n2] = MF(af[m2], bfr[n2], acc[m2][n2]);
    __syncthreads();
  }
#pragma unroll
  for (int m2 = 0; m2 < 4; ++m2)
#pragma unroll
    for (int n2 = 0; n2 < 4; ++n2) {
      size_t r0 = (size_t)(row0 + wr * 64 + m2 * 16 + fq * 4);
      size_t c0 = (size_t)(col0 + wc * 64 + n2 * 16 + fr);
#pragma unroll
      for (int i = 0; i < 4; ++i) C[(r0 + i) * NDIM + c0] = acc[m2][n2][i];
    }
}

// ---------------- launch ----------------

extern "C" void kernel_launch(void* const* d_in, const int* in_sizes, int n_in,
                              void* d_out, int out_size, void* d_ws, size_t ws_size,
                              hipStream_t stream) {
  const float* input  = (const float*)d_in[0];
  const float* weight = (const float*)d_in[1];
  const int*   mask   = (const int*)d_in[2];
  float* out = (float*)d_out;

  const size_t needA = (size_t)MDIM * KDIM * sizeof(unsigned short);
  const size_t needB = (size_t)NDIM * KDIM * sizeof(unsigned short);

  if (ws_size >= needA + needB) {
    unsigned short* Abf = (unsigned short*)d_ws;
    unsigned short* Bbf = (unsigned short*)((char*)d_ws + needA);
    convert_input_kernel<<<(MDIM * (size_t)KDIM / 8) / 256, 256, 0, stream>>>(input, Abf);
    convert_weight_kernel<<<(NDIM * (size_t)KDIM / 8) / 256, 256, 0, stream>>>(weight, mask, Bbf);
    gemm_breg<<<GRID_X, 512, 0, stream>>>(Abf, Bbf, out);
  } else {
    int nwg = (MDIM / 128) * (NDIM / 128);
    gemm_fused_fallback<<<nwg, 256, 0, stream>>>(input, weight, mask, out);
  }
}

// Round 11
// 174.575 us; speedup vs baseline: 1.3454x; 1.3454x over previous
//
#include <hip/hip_runtime.h>

// ExpanderLinearLayer: out[M,N] = input[M,K] @ (W[N,K]*mask[N,K])^T
// M=16384, N=2048, K=2048, fp32 in/out.
// bf16 conversion + 256x256 MFMA GEMM (16x16x32), 64 phases of
// {12 asm ds_read_b128; STG; VMCNT(8); bar; lgkmcnt(0)+sched_barrier;
//  32 MFMA; bar}. KEY CHANGE (R10 post-mortem): frag loads are INLINE ASM
// with hand-counted waits -- plain-C++ ds_reads let hipcc insert conservative
// alias waitcnts vs in-flight global_load_lds, serializing reads behind MFMA
// in every source-level schedule (R2-R9: constant ~45 cyc/MFMA/SIMD vs 19.4
// ideal). Asm reads are opaque to the compiler; ordering is ours alone.

#define MDIM 16384
#define NDIM 2048
#define KDIM 2048

#define BM 256
#define BN 256
#define GRID_X ((MDIM / BM) * (NDIM / BN))  // 64*8 = 512

using f32x4   = __attribute__((ext_vector_type(4))) float;
using bf16x8  = __attribute__((ext_vector_type(8))) __bf16;
using ushort8 = __attribute__((ext_vector_type(8))) unsigned short;

typedef __attribute__((address_space(3))) const unsigned short* lds_cptr_t;

__device__ __forceinline__ unsigned short f2bf(float f) {
  unsigned int u = __builtin_bit_cast(unsigned int, f);
  u = u + 0x7FFFu + ((u >> 16) & 1u);  // RNE
  return (unsigned short)(u >> 16);
}

// ---------------- conversion kernels ----------------

__global__ void convert_input_kernel(const float* __restrict__ in,
                                     unsigned short* __restrict__ out) {
  size_t base = ((size_t)blockIdx.x * blockDim.x + threadIdx.x) * 8;
  float4 a = *reinterpret_cast<const float4*>(in + base);
  float4 b = *reinterpret_cast<const float4*>(in + base + 4);
  ushort8 v;
  v[0] = f2bf(a.x); v[1] = f2bf(a.y); v[2] = f2bf(a.z); v[3] = f2bf(a.w);
  v[4] = f2bf(b.x); v[5] = f2bf(b.y); v[6] = f2bf(b.z); v[7] = f2bf(b.w);
  *reinterpret_cast<ushort8*>(out + base) = v;
}

__global__ void convert_weight_kernel(const float* __restrict__ w,
                                      const int* __restrict__ mk,
                                      unsigned short* __restrict__ out) {
  size_t base = ((size_t)blockIdx.x * blockDim.x + threadIdx.x) * 8;
  float4 a = *reinterpret_cast<const float4*>(w + base);
  float4 b = *reinterpret_cast<const float4*>(w + base + 4);
  int4 m0 = *reinterpret_cast<const int4*>(mk + base);
  int4 m1 = *reinterpret_cast<const int4*>(mk + base + 4);
  ushort8 v;
  v[0] = m0.x ? f2bf(a.x) : (unsigned short)0;
  v[1] = m0.y ? f2bf(a.y) : (unsigned short)0;
  v[2] = m0.z ? f2bf(a.z) : (unsigned short)0;
  v[3] = m0.w ? f2bf(a.w) : (unsigned short)0;
  v[4] = m1.x ? f2bf(b.x) : (unsigned short)0;
  v[5] = m1.y ? f2bf(b.y) : (unsigned short)0;
  v[6] = m1.z ? f2bf(b.z) : (unsigned short)0;
  v[7] = m1.w ? f2bf(b.w) : (unsigned short)0;
  *reinterpret_cast<ushort8*>(out + base) = v;
}

// ---------------- asm-read GEMM ----------------

__device__ __forceinline__ f32x4 MF(bf16x8 a, bf16x8 b, f32x4 c) {
  return __builtin_amdgcn_mfma_f32_16x16x32_bf16(a, b, c, 0, 0, 0);
}
#define VMCNT(n) asm volatile("s_waitcnt vmcnt(" #n ")" ::: "memory")
// asm ds_read: AS(3) pointer operand (32-bit byte addr), compile-time offset.
#define DSR(dst, p, off)                                                        \
  asm volatile("ds_read_b128 %0, %1 offset:%2" : "=v"(dst) : "v"(p), "i"(off))

// LDS: per operand 4 slots [buf(2)][khalf(2)] of 256 rows x 32 k bf16
// (16 KiB each). Slot (b,kh) byte base = (b*2+kh)*16384 (offset immediate).
// Swizzle (verified conflict-free R3): 16-B chunk' = chunk ^ ((row>>1)&3),
// applied on pre-swizzled global source (gload_lds dest linear) + ds_read.
// Schedule = R6's verified one: slot staged at t-3, retired by VMCNT(8) at
// t-1, published by t-1's trailing barrier, read at top of phase t.
__global__ __launch_bounds__(512, 2) void gemm_asm(
    const unsigned short* __restrict__ Abf,
    const unsigned short* __restrict__ Bbf,
    float* __restrict__ C) {
  __shared__ __attribute__((aligned(16))) unsigned short Asl[4 * 8192];
  __shared__ __attribute__((aligned(16))) unsigned short Bsl[4 * 8192];

  // bijective XCD swizzle (512 % 8 == 0) -- R3's proven map (FETCH ~98 MB)
  int bid = blockIdx.x;
  int wgs = (bid & 7) * (GRID_X / 8) + (bid >> 3);
  int tm = wgs >> 3;  // NDIM/BN == 8
  int tn = wgs & 7;
  int row0 = tm * BM, col0 = tn * BN;

  int t = threadIdx.x;
  int lane = t & 63, wid = t >> 6;
  int wr = wid >> 2, wc = wid & 3;       // 2 x 4 wave grid, wave tile 128x64
  int fr = lane & 15, fq = lane >> 4;

  // staging: thread covers chunks p0 and p0+64 (rows r0, r0+16; swizzle key
  // (r>>1)&3 invariant under +16 rows -> same inverse-swizzled k-chunk).
  int p0 = (wid * 2) * 64 + lane;
  int r0 = p0 >> 2, kc0 = ((p0 & 3) ^ ((r0 >> 1) & 3)) * 8;
  size_t offA0 = (size_t)(row0 + r0) * KDIM + kc0;
  size_t offB0 = (size_t)(col0 + r0) * KDIM + kc0;
  int ldsw0 = (wid * 2) * 512;  // elements; wave-uniform

  // frag ds_read base addrs (AS3, byte); per-slot/per-frag via offset: imm
  int kxor = (fq ^ ((fr >> 1) & 3)) * 8;
  int aoff = (wr * 128 + fr) * 32 + kxor;   // elements
  int boff = (wc * 64 + fr) * 32 + kxor;
  lds_cptr_t aA = ((lds_cptr_t)Asl) + aoff;
  lds_cptr_t aB = ((lds_cptr_t)Bsl) + boff;

  f32x4 acc[8][4];
#pragma unroll
  for (int m = 0; m < 8; ++m)
#pragma unroll
    for (int n = 0; n < 4; ++n) acc[m][n] = f32x4{0.f, 0.f, 0.f, 0.f};

#define SLOT_A(b, kh) (Asl + ((b) * 2 + (kh)) * 8192)
#define SLOT_B(b, kh) (Bsl + ((b) * 2 + (kh)) * 8192)

#define STG(slot, base, o0, ke) do {                                            \
  __builtin_amdgcn_global_load_lds(                                             \
      (const __attribute__((address_space(1))) void*)((base) + (o0) + (ke)),    \
      (__attribute__((address_space(3))) void*)((slot) + ldsw0), 16, 0, 0);     \
  __builtin_amdgcn_global_load_lds(                                             \
      (const __attribute__((address_space(1))) void*)((base) + (o0) + 32768 +   \
                                                      (ke)),                    \
      (__attribute__((address_space(3))) void*)((slot) + ldsw0 + 512), 16, 0,   \
      0);                                                                       \
} while (0)

// phase (buf b, khalf kh): 12 asm ds_read_b128 (slot published at t-1), then
// STG/VMCNT/bar, lgkmcnt(0)+sched_barrier(0) (rule #18), 32 reg-only MFMA.
#define PHASE(b, kh, STAGES, WAITS) do {                                        \
  bf16x8 _afr[8], _bfr[4];                                                      \
  DSR(_afr[0], aA, ((b) * 2 + (kh)) * 16384 + 0 * 1024);                        \
  DSR(_afr[1], aA, ((b) * 2 + (kh)) * 16384 + 1 * 1024);                        \
  DSR(_afr[2], aA, ((b) * 2 + (kh)) * 16384 + 2 * 1024);                        \
  DSR(_afr[3], aA, ((b) * 2 + (kh)) * 16384 + 3 * 1024);                        \
  DSR(_afr[4], aA, ((b) * 2 + (kh)) * 16384 + 4 * 1024);                        \
  DSR(_afr[5], aA, ((b) * 2 + (kh)) * 16384 + 5 * 1024);                        \
  DSR(_afr[6], aA, ((b) * 2 + (kh)) * 16384 + 6 * 1024);                        \
  DSR(_afr[7], aA, ((b) * 2 + (kh)) * 16384 + 7 * 1024);                        \
  DSR(_bfr[0], aB, ((b) * 2 + (kh)) * 16384 + 0 * 1024);                        \
  DSR(_bfr[1], aB, ((b) * 2 + (kh)) * 16384 + 1 * 1024);                        \
  DSR(_bfr[2], aB, ((b) * 2 + (kh)) * 16384 + 2 * 1024);                        \
  DSR(_bfr[3], aB, ((b) * 2 + (kh)) * 16384 + 3 * 1024);                        \
  STAGES;                                                                       \
  WAITS;                                                                        \
  __builtin_amdgcn_s_barrier();                                                 \
  asm volatile("s_waitcnt lgkmcnt(0)" ::: "memory");                            \
  __builtin_amdgcn_sched_barrier(0);                                            \
  __builtin_amdgcn_s_setprio(1);                                                \
  _Pragma("unroll")                                                             \
  for (int _m = 0; _m < 8; ++_m)                                                \
    _Pragma("unroll")                                                           \
    for (int _n = 0; _n < 4; ++_n)                                              \
      acc[_m][_n] = MF(_afr[_m], _bfr[_n], acc[_m][_n]);                        \
  __builtin_amdgcn_s_setprio(0);                                                \
  __builtin_amdgcn_s_barrier();                                                 \
} while (0)

  // prologue: stage slots (0,0),(0,1),(1,0) A+B = 12 vmem ops; retire slot
  // (0,0) (VMCNT(8)) and publish.
  STG(SLOT_A(0, 0), Abf, offA0, 0);
  STG(SLOT_B(0, 0), Bbf, offB0, 0);
  STG(SLOT_A(0, 1), Abf, offA0, 32);
  STG(SLOT_B(0, 1), Bbf, offB0, 32);
  STG(SLOT_A(1, 0), Abf, offA0, 64);
  STG(SLOT_B(1, 0), Bbf, offB0, 64);
  VMCNT(8);
  __builtin_amdgcn_s_barrier();

  // main loop (R6-verified schedule): before each VMCNT(8): 12 outstanding
  // (3 slots); it retires exactly the slot read in the NEXT phase.
  for (int i = 0; i < 15; ++i) {
    int kb = i * 128;
    PHASE(0, 0, { STG(SLOT_A(1, 1), Abf, offA0, kb + 96);
                  STG(SLOT_B(1, 1), Bbf, offB0, kb + 96); }, VMCNT(8));
    PHASE(0, 1, { STG(SLOT_A(0, 0), Abf, offA0, kb + 128);
                  STG(SLOT_B(0, 0), Bbf, offB0, kb + 128); }, VMCNT(8));
    PHASE(1, 0, { STG(SLOT_A(0, 1), Abf, offA0, kb + 160);
                  STG(SLOT_B(0, 1), Bbf, offB0, kb + 160); }, VMCNT(8));
    PHASE(1, 1, { STG(SLOT_A(1, 0), Abf, offA0, kb + 192);
                  STG(SLOT_B(1, 0), Bbf, offB0, kb + 192); }, VMCNT(8));
  }
  {  // tail iteration: only (1,1) still needs staging; drain 8 -> 4 -> 0
    int kb = (15) * 128;
    PHASE(0, 0, { STG(SLOT_A(1, 1), Abf, offA0, kb + 96);
                  STG(SLOT_B(1, 1), Bbf, offB0, kb + 96); }, VMCNT(8));
    PHASE(0, 1, , VMCNT(4));
    PHASE(1, 0, , VMCNT(0));
    PHASE(1, 1, , );
  }

  // epilogue: C/D layout (verified m89) col=lane&15, row=(lane>>4)*4+reg
  size_t crow = (size_t)(row0 + wr * 128 + fq * 4);
  int ccol = col0 + wc * 64 + fr;
#pragma unroll
  for (int m = 0; m < 8; ++m)
#pragma unroll
    for (int n = 0; n < 4; ++n) {
      float* cp = C + (crow + m * 16) * NDIM + ccol + n * 16;
#pragma unroll
      for (int e = 0; e < 4; ++e) cp[(size_t)e * NDIM] = acc[m][n][e];
    }
#undef PHASE
#undef STG
#undef SLOT_A
#undef SLOT_B
}

// ---------------- fallback (fused conversion, 128^2 m97-structure) ----------

__global__ __launch_bounds__(256) void gemm_fused_fallback(
    const float* __restrict__ Afp,
    const float* __restrict__ Wfp,
    const int* __restrict__ Mk,
    float* __restrict__ C) {
  __shared__ unsigned short As[128 * 32];
  __shared__ unsigned short Bs[128 * 32];
  int bid = blockIdx.x;
  int nwg = (MDIM / 128) * (NDIM / 128);
  int wg = (bid & 7) * (nwg / 8) + (bid >> 3);
  int tm = wg >> 4, tn = wg & 15;
  int row0 = tm * 128, col0 = tn * 128;
  int t = threadIdx.x;
  int lane = t & 63, wv = t >> 6;
  int wr = wv >> 1, wc = wv & 1;
  int fr = lane & 15, fq = lane >> 4;
  f32x4 acc[4][4];
#pragma unroll
  for (int i = 0; i < 4; ++i)
#pragma unroll
    for (int j = 0; j < 4; ++j) acc[i][j] = f32x4{0.f, 0.f, 0.f, 0.f};
  for (int kt = 0; kt < KDIM; kt += 32) {
#pragma unroll
    for (int j = 0; j < 2; ++j) {
      int c = j * 256 + t;
      int r = c >> 2;
      int ko = (c & 3) * 8;
      const float* ga = Afp + (size_t)(row0 + r) * KDIM + kt + ko;
      float4 a0 = *reinterpret_cast<const float4*>(ga);
      float4 a1 = *reinterpret_cast<const float4*>(ga + 4);
      ushort8 va;
      va[0] = f2bf(a0.x); va[1] = f2bf(a0.y); va[2] = f2bf(a0.z); va[3] = f2bf(a0.w);
      va[4] = f2bf(a1.x); va[5] = f2bf(a1.y); va[6] = f2bf(a1.z); va[7] = f2bf(a1.w);
      *reinterpret_cast<ushort8*>(As + (size_t)c * 8) = va;
      const float* gw = Wfp + (size_t)(col0 + r) * KDIM + kt + ko;
      const int* gm = Mk + (size_t)(col0 + r) * KDIM + kt + ko;
      float4 w0 = *reinterpret_cast<const float4*>(gw);
      float4 w1 = *reinterpret_cast<const float4*>(gw + 4);
      int4 m0 = *reinterpret_cast<const int4*>(gm);
      int4 m1 = *reinterpret_cast<const int4*>(gm + 4);
      ushort8 vb;
      vb[0] = m0.x ? f2bf(w0.x) : (unsigned short)0;
      vb[1] = m0.y ? f2bf(w0.y) : (unsigned short)0;
      vb[2] = m0.z ? f2bf(w0.z) : (unsigned short)0;
      vb[3] = m0.w ? f2bf(w0.w) : (unsigned short)0;
      vb[4] = m1.x ? f2bf(w1.x) : (unsigned short)0;
      vb[5] = m1.y ? f2bf(w1.y) : (unsigned short)0;
      vb[6] = m1.z ? f2bf(w1.z) : (unsigned short)0;
      vb[7] = m1.w ? f2bf(w1.w) : (unsigned short)0;
      *reinterpret_cast<ushort8*>(Bs + (size_t)c * 8) = vb;
    }
    __syncthreads();
    bf16x8 af[4], bfr[4];
#pragma unroll
    for (int m2 = 0; m2 < 4; ++m2)
      af[m2] = *reinterpret_cast<const bf16x8*>(As + (wr * 64 + m2 * 16 + fr) * 32 + fq * 8);
#pragma unroll
    for (int n2 = 0; n2 < 4; ++n2)
      bfr[n2] = *reinterpret_cast<const bf16x8*>(Bs + (wc * 64 + n2 * 16 + fr) * 32 + fq * 8);
#pragma unroll
    for (int m2 = 0; m2 < 4; ++m2)
#pragma unroll
      for (int n2 = 0; n2 < 4; ++n2)
        acc[m2][n2] = MF(af[m2], bfr[n2], acc[m2][n2]);
    __syncthreads();
  }
#pragma unroll
  for (int m2 = 0; m2 < 4; ++m2)
#pragma unroll
    for (int n2 = 0; n2 < 4; ++n2) {
      size_t r0 = (size_t)(row0 + wr * 64 + m2 * 16 + fq * 4);
      size_t c0 = (size_t)(col0 + wc * 64 + n2 * 16 + fr);
#pragma unroll
      for (int i = 0; i < 4; ++i) C[(r0 + i) * NDIM + c0] = acc[m2][n2][i];
    }
}

// ---------------- launch ----------------

extern "C" void kernel_launch(void* const* d_in, const int* in_sizes, int n_in,
                              void* d_out, int out_size, void* d_ws, size_t ws_size,
                              hipStream_t stream) {
  const float* input  = (const float*)d_in[0];
  const float* weight = (const float*)d_in[1];
  const int*   mask   = (const int*)d_in[2];
  float* out = (float*)d_out;

  const size_t needA = (size_t)MDIM * KDIM * sizeof(unsigned short);
  const size_t needB = (size_t)NDIM * KDIM * sizeof(unsigned short);

  if (ws_size >= needA + needB) {
    unsigned short* Abf = (unsigned short*)d_ws;
    unsigned short* Bbf = (unsigned short*)((char*)d_ws + needA);
    convert_input_kernel<<<(MDIM * (size_t)KDIM / 8) / 256, 256, 0, stream>>>(input, Abf);
    convert_weight_kernel<<<(NDIM * (size_t)KDIM / 8) / 256, 256, 0, stream>>>(weight, mask, Bbf);
    gemm_asm<<<GRID_X, 512, 0, stream>>>(Abf, Bbf, out);
  } else {
    int nwg = (MDIM / 128) * (NDIM / 128);
    gemm_fused_fallback<<<nwg, 256, 0, stream>>>(input, weight, mask, out);
  }
}

// Round 12
// 173.067 us; speedup vs baseline: 1.3572x; 1.0087x over previous
//
#include <hip/hip_runtime.h>

// ExpanderLinearLayer: out[M,N] = input[M,K] @ (W[N,K]*mask[N,K])^T
// M=16384, N=2048, K=2048, fp32 in/out.
// bf16 conversion + 256x256 MFMA GEMM (16x16x32). 64 phases of
// {STG(t+3); VMCNT(8); barA; lgkmcnt(0); 32 MFMA with 12 asm ds_read_b128
//  for slot t+1 INSIDE the cluster; barB}. Frag regs double-buffered (P/Q):
// reads issued during phase t are awaited by phase t+1's lgkmcnt -- a full
// MFMA window of slack -- so the 1152-cyc LDS drain hides under the 1242-cyc
// MFMA window (R11 measured them serialized: reads + same-phase lgkm + MFMA).

#define MDIM 16384
#define NDIM 2048
#define KDIM 2048

#define BM 256
#define BN 256
#define GRID_X ((MDIM / BM) * (NDIM / BN))  // 64*8 = 512

using f32x4   = __attribute__((ext_vector_type(4))) float;
using bf16x8  = __attribute__((ext_vector_type(8))) __bf16;
using ushort8 = __attribute__((ext_vector_type(8))) unsigned short;

typedef __attribute__((address_space(3))) const unsigned short* lds_cptr_t;

__device__ __forceinline__ unsigned short f2bf(float f) {
  unsigned int u = __builtin_bit_cast(unsigned int, f);
  u = u + 0x7FFFu + ((u >> 16) & 1u);  // RNE
  return (unsigned short)(u >> 16);
}

// ---------------- conversion kernels ----------------

__global__ void convert_input_kernel(const float* __restrict__ in,
                                     unsigned short* __restrict__ out) {
  size_t base = ((size_t)blockIdx.x * blockDim.x + threadIdx.x) * 8;
  float4 a = *reinterpret_cast<const float4*>(in + base);
  float4 b = *reinterpret_cast<const float4*>(in + base + 4);
  ushort8 v;
  v[0] = f2bf(a.x); v[1] = f2bf(a.y); v[2] = f2bf(a.z); v[3] = f2bf(a.w);
  v[4] = f2bf(b.x); v[5] = f2bf(b.y); v[6] = f2bf(b.z); v[7] = f2bf(b.w);
  *reinterpret_cast<ushort8*>(out + base) = v;
}

__global__ void convert_weight_kernel(const float* __restrict__ w,
                                      const int* __restrict__ mk,
                                      unsigned short* __restrict__ out) {
  size_t base = ((size_t)blockIdx.x * blockDim.x + threadIdx.x) * 8;
  float4 a = *reinterpret_cast<const float4*>(w + base);
  float4 b = *reinterpret_cast<const float4*>(w + base + 4);
  int4 m0 = *reinterpret_cast<const int4*>(mk + base);
  int4 m1 = *reinterpret_cast<const int4*>(mk + base + 4);
  ushort8 v;
  v[0] = m0.x ? f2bf(a.x) : (unsigned short)0;
  v[1] = m0.y ? f2bf(a.y) : (unsigned short)0;
  v[2] = m0.z ? f2bf(a.z) : (unsigned short)0;
  v[3] = m0.w ? f2bf(a.w) : (unsigned short)0;
  v[4] = m1.x ? f2bf(b.x) : (unsigned short)0;
  v[5] = m1.y ? f2bf(b.y) : (unsigned short)0;
  v[6] = m1.z ? f2bf(b.z) : (unsigned short)0;
  v[7] = m1.w ? f2bf(b.w) : (unsigned short)0;
  *reinterpret_cast<ushort8*>(out + base) = v;
}

// ---------------- read-ahead asm GEMM ----------------

__device__ __forceinline__ f32x4 MF(bf16x8 a, bf16x8 b, f32x4 c) {
  return __builtin_amdgcn_mfma_f32_16x16x32_bf16(a, b, c, 0, 0, 0);
}
#define VMCNT(n) asm volatile("s_waitcnt vmcnt(" #n ")" ::: "memory")
#define DSR(dst, p, off)                                                        \
  asm volatile("ds_read_b128 %0, %1 offset:%2" : "=v"(dst) : "v"(p), "i"(off))

// LDS: per operand 4 slots [buf(2)][khalf(2)] of 256 rows x 32 k bf16
// (16 KiB each); slot (b,kh) byte base = (b*2+kh)*16384 (offset immediate).
// Swizzle (verified conflict-free R3): 16-B chunk' = chunk ^ ((row>>1)&3),
// on pre-swizzled global source (gload_lds dest linear) + ds_read addrs.
// Schedule (R6/R11-verified): slot staged at t-3, retired by VMCNT(8) at
// t-1, published by t-1's barrier A; READ during t-1's cluster (read-ahead);
// consumed at t after lgkmcnt(0).
__global__ __launch_bounds__(512, 2) void gemm_ra(
    const unsigned short* __restrict__ Abf,
    const unsigned short* __restrict__ Bbf,
    float* __restrict__ C) {
  __shared__ __attribute__((aligned(16))) unsigned short Asl[4 * 8192];
  __shared__ __attribute__((aligned(16))) unsigned short Bsl[4 * 8192];

  // bijective XCD swizzle (512 % 8 == 0) -- R3's proven map (FETCH ~98 MB)
  int bid = blockIdx.x;
  int wgs = (bid & 7) * (GRID_X / 8) + (bid >> 3);
  int tm = wgs >> 3;  // NDIM/BN == 8
  int tn = wgs & 7;
  int row0 = tm * BM, col0 = tn * BN;

  int t = threadIdx.x;
  int lane = t & 63, wid = t >> 6;
  int wr = wid >> 2, wc = wid & 3;       // 2 x 4 wave grid, wave tile 128x64
  int fr = lane & 15, fq = lane >> 4;

  // staging: thread covers chunks p0 and p0+64 (rows r0, r0+16; swizzle key
  // (r>>1)&3 invariant under +16 rows -> same inverse-swizzled k-chunk).
  int p0 = (wid * 2) * 64 + lane;
  int r0 = p0 >> 2, kc0 = ((p0 & 3) ^ ((r0 >> 1) & 3)) * 8;
  size_t offA0 = (size_t)(row0 + r0) * KDIM + kc0;
  size_t offB0 = (size_t)(col0 + r0) * KDIM + kc0;
  int ldsw0 = (wid * 2) * 512;  // elements; wave-uniform

  // frag ds_read base addrs (AS3); per-slot/per-frag via offset: immediate
  int kxor = (fq ^ ((fr >> 1) & 3)) * 8;
  int aoff = (wr * 128 + fr) * 32 + kxor;   // elements
  int boff = (wc * 64 + fr) * 32 + kxor;
  lds_cptr_t aA = ((lds_cptr_t)Asl) + aoff;
  lds_cptr_t aB = ((lds_cptr_t)Bsl) + boff;

  f32x4 acc[8][4];
#pragma unroll
  for (int m = 0; m < 8; ++m)
#pragma unroll
    for (int n = 0; n < 4; ++n) acc[m][n] = f32x4{0.f, 0.f, 0.f, 0.f};

  bf16x8 aP[8], bP[4], aQ[8], bQ[4];  // double-buffered frag registers

#define SLOT_A(b, kh) (Asl + ((b) * 2 + (kh)) * 8192)
#define SLOT_B(b, kh) (Bsl + ((b) * 2 + (kh)) * 8192)

#define STG(slot, base, o0, ke) do {                                            \
  __builtin_amdgcn_global_load_lds(                                             \
      (const __attribute__((address_space(1))) void*)((base) + (o0) + (ke)),    \
      (__attribute__((address_space(3))) void*)((slot) + ldsw0), 16, 0, 0);     \
  __builtin_amdgcn_global_load_lds(                                             \
      (const __attribute__((address_space(1))) void*)((base) + (o0) + 32768 +   \
                                                      (ke)),                    \
      (__attribute__((address_space(3))) void*)((slot) + ldsw0 + 512), 16, 0,   \
      0);                                                                       \
} while (0)

// 12 asm reads of slot (b,kh) into (AD, BD)
#define RD12(b, kh, AD, BD) do {                                                \
  DSR(AD[0], aA, ((b) * 2 + (kh)) * 16384 + 0 * 1024);                          \
  DSR(AD[1], aA, ((b) * 2 + (kh)) * 16384 + 1 * 1024);                          \
  DSR(AD[2], aA, ((b) * 2 + (kh)) * 16384 + 2 * 1024);                          \
  DSR(AD[3], aA, ((b) * 2 + (kh)) * 16384 + 3 * 1024);                          \
  DSR(AD[4], aA, ((b) * 2 + (kh)) * 16384 + 4 * 1024);                          \
  DSR(AD[5], aA, ((b) * 2 + (kh)) * 16384 + 5 * 1024);                          \
  DSR(AD[6], aA, ((b) * 2 + (kh)) * 16384 + 6 * 1024);                          \
  DSR(AD[7], aA, ((b) * 2 + (kh)) * 16384 + 7 * 1024);                          \
  DSR(BD[0], aB, ((b) * 2 + (kh)) * 16384 + 0 * 1024);                          \
  DSR(BD[1], aB, ((b) * 2 + (kh)) * 16384 + 1 * 1024);                          \
  DSR(BD[2], aB, ((b) * 2 + (kh)) * 16384 + 2 * 1024);                          \
  DSR(BD[3], aB, ((b) * 2 + (kh)) * 16384 + 3 * 1024);                          \
} while (0)

// phase t: STG(t+3); VMCNT retires slot t+1; barA publishes it; lgkmcnt(0)
// completes the frags read DURING t-1's cluster (AC,BC); cluster = 16 MFMA,
// then 12 asm reads of slot t+1 (rb,rkh) into (AD,BD), then 16 MFMA; barB.
#define PHASE(rb, rkh, AC, BC, AD, BD, STAGES, WAITS) do {                      \
  STAGES;                                                                       \
  WAITS;                                                                        \
  __builtin_amdgcn_s_barrier();                                                 \
  asm volatile("s_waitcnt lgkmcnt(0)" ::: "memory");                            \
  __builtin_amdgcn_sched_barrier(0);                                            \
  __builtin_amdgcn_s_setprio(1);                                                \
  _Pragma("unroll")                                                             \
  for (int _m = 0; _m < 4; ++_m)                                                \
    _Pragma("unroll")                                                           \
    for (int _n = 0; _n < 4; ++_n)                                              \
      acc[_m][_n] = MF(AC[_m], BC[_n], acc[_m][_n]);                            \
  RD12(rb, rkh, AD, BD);                                                        \
  _Pragma("unroll")                                                             \
  for (int _m = 4; _m < 8; ++_m)                                                \
    _Pragma("unroll")                                                           \
    for (int _n = 0; _n < 4; ++_n)                                              \
      acc[_m][_n] = MF(AC[_m], BC[_n], acc[_m][_n]);                            \
  __builtin_amdgcn_s_setprio(0);                                                \
  __builtin_amdgcn_s_barrier();                                                 \
} while (0)

  // prologue: stage slots (0,0),(0,1),(1,0) = 12 vmem ops; retire slot (0,0)
  // (VMCNT(8)), publish, then asm-read its frags into P (awaited by phase
  // 0's lgkmcnt(0)).
  STG(SLOT_A(0, 0), Abf, offA0, 0);
  STG(SLOT_B(0, 0), Bbf, offB0, 0);
  STG(SLOT_A(0, 1), Abf, offA0, 32);
  STG(SLOT_B(0, 1), Bbf, offB0, 32);
  STG(SLOT_A(1, 0), Abf, offA0, 64);
  STG(SLOT_B(1, 0), Bbf, offB0, 64);
  VMCNT(8);
  __builtin_amdgcn_s_barrier();
  RD12(0, 0, aP, bP);

  // main loop: phases t=0..59. Consume slot t (regs), read-ahead slot t+1.
  for (int i = 0; i < 15; ++i) {
    int kb = i * 128;
    PHASE(0, 1, aP, bP, aQ, bQ, { STG(SLOT_A(1, 1), Abf, offA0, kb + 96);
                                  STG(SLOT_B(1, 1), Bbf, offB0, kb + 96); },
          VMCNT(8));
    PHASE(1, 0, aQ, bQ, aP, bP, { STG(SLOT_A(0, 0), Abf, offA0, kb + 128);
                                  STG(SLOT_B(0, 0), Bbf, offB0, kb + 128); },
          VMCNT(8));
    PHASE(1, 1, aP, bP, aQ, bQ, { STG(SLOT_A(0, 1), Abf, offA0, kb + 160);
                                  STG(SLOT_B(0, 1), Bbf, offB0, kb + 160); },
          VMCNT(8));
    PHASE(0, 0, aQ, bQ, aP, bP, { STG(SLOT_A(1, 0), Abf, offA0, kb + 192);
                                  STG(SLOT_B(1, 0), Bbf, offB0, kb + 192); },
          VMCNT(8));
  }
  // tail: t=60..62 (drain 8 -> 4 -> 0), then bare cluster at t=63.
  PHASE(0, 1, aP, bP, aQ, bQ, { STG(SLOT_A(1, 1), Abf, offA0, 2016);
                                STG(SLOT_B(1, 1), Bbf, offB0, 2016); },
        VMCNT(8));
  PHASE(1, 0, aQ, bQ, aP, bP, , VMCNT(4));
  PHASE(1, 1, aP, bP, aQ, bQ, , VMCNT(0));
  {
    asm volatile("s_waitcnt lgkmcnt(0)" ::: "memory");
    __builtin_amdgcn_sched_barrier(0);
#pragma unroll
    for (int m = 0; m < 8; ++m)
#pragma unroll
      for (int n = 0; n < 4; ++n)
        acc[m][n] = MF(aQ[m], bQ[n], acc[m][n]);
  }

  // epilogue: C/D layout (verified m89) col=lane&15, row=(lane>>4)*4+reg
  size_t crow = (size_t)(row0 + wr * 128 + fq * 4);
  int ccol = col0 + wc * 64 + fr;
#pragma unroll
  for (int m = 0; m < 8; ++m)
#pragma unroll
    for (int n = 0; n < 4; ++n) {
      float* cp = C + (crow + m * 16) * NDIM + ccol + n * 16;
#pragma unroll
      for (int e = 0; e < 4; ++e) cp[(size_t)e * NDIM] = acc[m][n][e];
    }
#undef PHASE
#undef RD12
#undef STG
#undef SLOT_A
#undef SLOT_B
}

// ---------------- fallback (fused conversion, 128^2 m97-structure) ----------

__global__ __launch_bounds__(256) void gemm_fused_fallback(
    const float* __restrict__ Afp,
    const float* __restrict__ Wfp,
    const int* __restrict__ Mk,
    float* __restrict__ C) {
  __shared__ unsigned short As[128 * 32];
  __shared__ unsigned short Bs[128 * 32];
  int bid = blockIdx.x;
  int nwg = (MDIM / 128) * (NDIM / 128);
  int wg = (bid & 7) * (nwg / 8) + (bid >> 3);
  int tm = wg >> 4, tn = wg & 15;
  int row0 = tm * 128, col0 = tn * 128;
  int t = threadIdx.x;
  int lane = t & 63, wv = t >> 6;
  int wr = wv >> 1, wc = wv & 1;
  int fr = lane & 15, fq = lane >> 4;
  f32x4 acc[4][4];
#pragma unroll
  for (int i = 0; i < 4; ++i)
#pragma unroll
    for (int j = 0; j < 4; ++j) acc[i][j] = f32x4{0.f, 0.f, 0.f, 0.f};
  for (int kt = 0; kt < KDIM; kt += 32) {
#pragma unroll
    for (int j = 0; j < 2; ++j) {
      int c = j * 256 + t;
      int r = c >> 2;
      int ko = (c & 3) * 8;
      const float* ga = Afp + (size_t)(row0 + r) * KDIM + kt + ko;
      float4 a0 = *reinterpret_cast<const float4*>(ga);
      float4 a1 = *reinterpret_cast<const float4*>(ga + 4);
      ushort8 va;
      va[0] = f2bf(a0.x); va[1] = f2bf(a0.y); va[2] = f2bf(a0.z); va[3] = f2bf(a0.w);
      va[4] = f2bf(a1.x); va[5] = f2bf(a1.y); va[6] = f2bf(a1.z); va[7] = f2bf(a1.w);
      *reinterpret_cast<ushort8*>(As + (size_t)c * 8) = va;
      const float* gw = Wfp + (size_t)(col0 + r) * KDIM + kt + ko;
      const int* gm = Mk + (size_t)(col0 + r) * KDIM + kt + ko;
      float4 w0 = *reinterpret_cast<const float4*>(gw);
      float4 w1 = *reinterpret_cast<const float4*>(gw + 4);
      int4 m0 = *reinterpret_cast<const int4*>(gm);
      int4 m1 = *reinterpret_cast<const int4*>(gm + 4);
      ushort8 vb;
      vb[0] = m0.x ? f2bf(w0.x) : (unsigned short)0;
      vb[1] = m0.y ? f2bf(w0.y) : (unsigned short)0;
      vb[2] = m0.z ? f2bf(w0.z) : (unsigned short)0;
      vb[3] = m0.w ? f2bf(w0.w) : (unsigned short)0;
      vb[4] = m1.x ? f2bf(w1.x) : (unsigned short)0;
      vb[5] = m1.y ? f2bf(w1.y) : (unsigned short)0;
      vb[6] = m1.z ? f2bf(w1.z) : (unsigned short)0;
      vb[7] = m1.w ? f2bf(w1.w) : (unsigned short)0;
      *reinterpret_cast<ushort8*>(Bs + (size_t)c * 8) = vb;
    }
    __syncthreads();
    bf16x8 af[4], bfr[4];
#pragma unroll
    for (int m2 = 0; m2 < 4; ++m2)
      af[m2] = *reinterpret_cast<const bf16x8*>(As + (wr * 64 + m2 * 16 + fr) * 32 + fq * 8);
#pragma unroll
    for (int n2 = 0; n2 < 4; ++n2)
      bfr[n2] = *reinterpret_cast<const bf16x8*>(Bs + (wc * 64 + n2 * 16 + fr) * 32 + fq * 8);
#pragma unroll
    for (int m2 = 0; m2 < 4; ++m2)
#pragma unroll
      for (int n2 = 0; n2 < 4; ++n2)
        acc[m2][n2] = MF(af[m2], bfr[n2], acc[m2][n2]);
    __syncthreads();
  }
#pragma unroll
  for (int m2 = 0; m2 < 4; ++m2)
#pragma unroll
    for (int n2 = 0; n2 < 4; ++n2) {
      size_t r0 = (size_t)(row0 + wr * 64 + m2 * 16 + fq * 4);
      size_t c0 = (size_t)(col0 + wc * 64 + n2 * 16 + fr);
#pragma unroll
      for (int i = 0; i < 4; ++i) C[(r0 + i) * NDIM + c0] = acc[m2][n2][i];
    }
}

// ---------------- launch ----------------

extern "C" void kernel_launch(void* const* d_in, const int* in_sizes, int n_in,
                              void* d_out, int out_size, void* d_ws, size_t ws_size,
                              hipStream_t stream) {
  const float* input  = (const float*)d_in[0];
  const float* weight = (const float*)d_in[1];
  const int*   mask   = (const int*)d_in[2];
  float* out = (float*)d_out;

  const size_t needA = (size_t)MDIM * KDIM * sizeof(unsigned short);
  const size_t needB = (size_t)NDIM * KDIM * sizeof(unsigned short);

  if (ws_size >= needA + needB) {
    unsigned short* Abf = (unsigned short*)d_ws;
    unsigned short* Bbf = (unsigned short*)((char*)d_ws + needA);
    convert_input_kernel<<<(MDIM * (size_t)KDIM / 8) / 256, 256, 0, stream>>>(input, Abf);
    convert_weight_kernel<<<(NDIM * (size_t)KDIM / 8) / 256, 256, 0, stream>>>(weight, mask, Bbf);
    gemm_ra<<<GRID_X, 512, 0, stream>>>(Abf, Bbf, out);
  } else {
    int nwg = (MDIM / 128) * (NDIM / 128);
    gemm_fused_fallback<<<nwg, 256, 0, stream>>>(input, weight, mask, out);
  }
}